// Round 1
// baseline (198.881 us; speedup 1.0000x reference)
//
#include <hip/hip_runtime.h>

#define D_  256
#define H1_ 256
#define H2_ 128
#define B_  2
#define LQ_ 512
#define LK_ 512
#define BK  64

typedef float  f32x4  __attribute__((ext_vector_type(4)));
typedef __bf16 bf16x8 __attribute__((ext_vector_type(8)));
typedef __bf16 bf16x4 __attribute__((ext_vector_type(4)));

// ---- prep: qp = query@W1[:D] + b1 ; kp = key@W1[D:] ; w2t = bf16(W2^T) ----
__global__ void prep_kernel(const float* __restrict__ query,
                            const float* __restrict__ key,
                            const float* __restrict__ W1,
                            const float* __restrict__ b1,
                            const float* __restrict__ W2,
                            float* __restrict__ qp,
                            float* __restrict__ kp,
                            __bf16* __restrict__ w2t) {
  const int blk = blockIdx.x;
  const int tid = threadIdx.x;
  if (blk >= 256) {
    // 128 blocks x 256 threads = 32768 = H2*H1 elements of W2^T (bf16)
    const int id = (blk - 256) * 256 + tid;
    const int n = id >> 8;    // H2 index
    const int k = id & 255;   // H1 index
    w2t[n * H1_ + k] = (__bf16)W2[k * H2_ + n];
    return;
  }
  // blocks 0..255: each handles 8 rows of the 2048-row projection problem
  __shared__ float in_lds[8][D_];
  const int row0 = blk * 8;              // 0..2047 ; rows 0..1023 -> qp, 1024.. -> kp
  const int sel  = row0 >> 10;
  const float* __restrict__ src = sel ? key : query;
  const int base = (row0 & 1023) * D_;
  for (int i = tid; i < 8 * D_; i += 256)
    in_lds[i >> 8][i & 255] = src[base + i];
  __syncthreads();
  const int h = tid;  // output column 0..255
  float acc[8];
  const float bias = sel ? 0.0f : b1[h];  // fold b1 into qp
#pragma unroll
  for (int r = 0; r < 8; ++r) acc[r] = bias;
  const float* __restrict__ w = W1 + sel * D_ * H1_ + h;
#pragma unroll 4
  for (int d = 0; d < D_; ++d) {
    const float wv = w[d * H1_];
#pragma unroll
    for (int r = 0; r < 8; ++r) acc[r] += in_lds[r][d] * wv;
  }
  float* __restrict__ dst = sel ? kp : qp;
#pragma unroll
  for (int r = 0; r < 8; ++r) dst[base + r * D_ + h] = acc[r];
}

// ---- main fused kernel: scores[b, q0+qi, k0+ki] for 8 q x 16 k per block ----
// C-tile: 128 rows (pairs, row = qi*16+ki) x 128 cols (H2), K = H1 = 256.
// 4 waves, each 64x64 quadrant of 16x16x32 bf16 MFMAs; BK=64 K-chunks.
__global__ __launch_bounds__(256, 2) void score_kernel(
    const float* __restrict__ qp, const float* __restrict__ kp,
    const __bf16* __restrict__ w2t,
    const float* __restrict__ b2, const float* __restrict__ W3,
    const float* __restrict__ b3, float* __restrict__ scores) {
  __shared__ __bf16 A_lds[128][BK + 8];   // +8 bf16 pad -> 2-way bank aliasing (free)
  __shared__ __bf16 B_lds[128][BK + 8];
  __shared__ float  spart[2][128];

  const int b  = blockIdx.z;
  const int q0 = blockIdx.y * 8;
  const int k0 = blockIdx.x * 16;
  const int tid  = threadIdx.x;
  const int wave = tid >> 6;
  const int lane = tid & 63;
  const int quad = lane >> 4;
  const int l16  = lane & 15;
  const int wm   = wave >> 1;   // row half (0/1)
  const int wn   = wave & 1;    // col half (0/1)

  const float* __restrict__ qpb = qp + (b * LQ_ + q0) * H1_;
  const float* __restrict__ kpb = kp + (b * LK_ + k0) * H1_;

  f32x4 acc[4][4];
#pragma unroll
  for (int mt = 0; mt < 4; ++mt)
#pragma unroll
    for (int nt = 0; nt < 4; ++nt)
      acc[mt][nt] = (f32x4){0.f, 0.f, 0.f, 0.f};

  for (int kc = 0; kc < H1_ / BK; ++kc) {
    // --- form A tile: A[row][k] = relu(qp[qi][k] + kp[ki][k]) in bf16 ---
    // 128 rows x 16 float4-groups = 2048 groups, 8 per thread
#pragma unroll
    for (int i = 0; i < 8; ++i) {
      const int r  = i * 16 + (tid >> 4);   // 0..127
      const int kg = tid & 15;              // float4 group within BK
      const int qi = r >> 4, ki = r & 15;
      const int kcol = kc * BK + kg * 4;
      const float4 qv = *(const float4*)(qpb + qi * H1_ + kcol);
      const float4 kv = *(const float4*)(kpb + ki * H1_ + kcol);
      bf16x4 a;
      a[0] = (__bf16)fmaxf(qv.x + kv.x, 0.f);
      a[1] = (__bf16)fmaxf(qv.y + kv.y, 0.f);
      a[2] = (__bf16)fmaxf(qv.z + kv.z, 0.f);
      a[3] = (__bf16)fmaxf(qv.w + kv.w, 0.f);
      *(bf16x4*)(&A_lds[r][kg * 4]) = a;
    }
    // --- stage W2^T chunk: 128 rows x 64 bf16 = 1024 x 16B, 4 per thread ---
#pragma unroll
    for (int i = 0; i < 4; ++i) {
      const int u = i * 256 + tid;
      const int n = u >> 3, seg = u & 7;
      *(uint4*)(&B_lds[n][seg * 8]) =
          *(const uint4*)(w2t + n * H1_ + kc * BK + seg * 8);
    }
    __syncthreads();
    // --- MFMA over this chunk: 2 k-steps x (4x4) tiles ---
#pragma unroll
    for (int ks = 0; ks < BK / 32; ++ks) {
      bf16x8 af[4], bfr[4];
#pragma unroll
      for (int mt = 0; mt < 4; ++mt)
        af[mt] = *(const bf16x8*)(&A_lds[wm * 64 + mt * 16 + l16][ks * 32 + quad * 8]);
#pragma unroll
      for (int nt = 0; nt < 4; ++nt)
        bfr[nt] = *(const bf16x8*)(&B_lds[wn * 64 + nt * 16 + l16][ks * 32 + quad * 8]);
#pragma unroll
      for (int mt = 0; mt < 4; ++mt)
#pragma unroll
        for (int nt = 0; nt < 4; ++nt)
          acc[mt][nt] = __builtin_amdgcn_mfma_f32_16x16x32_bf16(
              af[mt], bfr[nt], acc[mt][nt], 0, 0, 0);
    }
    __syncthreads();
  }

  // --- epilogue: score_row = sum_n relu(h2 + b2[n]) * W3[n]  (+ b3) ---
  float part[4][4];  // [mt][reg]
#pragma unroll
  for (int mt = 0; mt < 4; ++mt)
#pragma unroll
    for (int rg = 0; rg < 4; ++rg) part[mt][rg] = 0.f;
#pragma unroll
  for (int nt = 0; nt < 4; ++nt) {
    const int col = wn * 64 + nt * 16 + l16;
    const float b2v = b2[col];
    const float w3v = W3[col];
#pragma unroll
    for (int mt = 0; mt < 4; ++mt)
#pragma unroll
      for (int rg = 0; rg < 4; ++rg) {
        float h2 = acc[mt][nt][rg] + b2v;
        h2 = fmaxf(h2, 0.f);
        part[mt][rg] += h2 * w3v;
      }
  }
  // reduce across the 16 lanes holding distinct cols (lane bits 0..3)
#pragma unroll
  for (int off = 1; off < 16; off <<= 1)
#pragma unroll
    for (int mt = 0; mt < 4; ++mt)
#pragma unroll
      for (int rg = 0; rg < 4; ++rg)
        part[mt][rg] += __shfl_xor(part[mt][rg], off, 64);
  if (l16 == 0) {
#pragma unroll
    for (int mt = 0; mt < 4; ++mt)
#pragma unroll
      for (int rg = 0; rg < 4; ++rg) {
        const int rl = wm * 64 + mt * 16 + quad * 4 + rg;
        spart[wn][rl] = part[mt][rg];
      }
  }
  __syncthreads();
  if (tid < 128) {
    const float s = spart[0][tid] + spart[1][tid] + b3[0];
    const int qi = tid >> 4, ki = tid & 15;
    scores[(b * LQ_ + q0 + qi) * LK_ + k0 + ki] = s;
  }
}

// ---- softmax over k per (b,q) row, with mask; in-place on the attn region ----
__global__ void softmax_kernel(float* __restrict__ attn,
                               const int* __restrict__ mask) {
  const int row = blockIdx.x;  // 0..B*LQ-1
  const int tid = threadIdx.x;
  __shared__ float redm[4];
  __shared__ float reds[4];
  float* __restrict__ arow = attn + row * LK_;
  const int* __restrict__ mrow = mask + row * LK_;
  float s0 = arow[tid], s1 = arow[tid + 256];
  if (mrow[tid] == 0)       s0 = -1e9f;
  if (mrow[tid + 256] == 0) s1 = -1e9f;
  float m = fmaxf(s0, s1);
#pragma unroll
  for (int off = 32; off; off >>= 1) m = fmaxf(m, __shfl_xor(m, off, 64));
  if ((tid & 63) == 0) redm[tid >> 6] = m;
  __syncthreads();
  m = fmaxf(fmaxf(redm[0], redm[1]), fmaxf(redm[2], redm[3]));
  const float e0 = __expf(s0 - m), e1 = __expf(s1 - m);
  float sum = e0 + e1;
#pragma unroll
  for (int off = 32; off; off >>= 1) sum += __shfl_xor(sum, off, 64);
  if ((tid & 63) == 0) reds[tid >> 6] = sum;
  __syncthreads();
  sum = reds[0] + reds[1] + reds[2] + reds[3];
  const float inv = 1.f / sum;
  arow[tid]       = e0 * inv;
  arow[tid + 256] = e1 * inv;
}

// ---- out = attn @ value : block handles (b, 8 q-rows), thread d column ----
__global__ void out_kernel(const float* __restrict__ attn,
                           const float* __restrict__ value,
                           float* __restrict__ out) {
  const int g = blockIdx.x;        // 0..127
  const int b = g >> 6, qg = g & 63;
  __shared__ float a_lds[8][LK_];
  const float* __restrict__ abase = attn + (b * LQ_ + qg * 8) * LK_;
  for (int i = threadIdx.x; i < 8 * LK_; i += 256)
    a_lds[i >> 9][i & 511] = abase[i];
  __syncthreads();
  const int d = threadIdx.x;
  float acc[8] = {0.f, 0.f, 0.f, 0.f, 0.f, 0.f, 0.f, 0.f};
  const float* __restrict__ vb = value + b * LK_ * D_ + d;
  for (int k = 0; k < LK_; ++k) {
    const float v = vb[k * D_];
#pragma unroll
    for (int q = 0; q < 8; ++q) acc[q] += a_lds[q][k] * v;
  }
  float* __restrict__ ob = out + (b * LQ_ + qg * 8) * D_ + d;
#pragma unroll
  for (int q = 0; q < 8; ++q) ob[q * D_] = acc[q];
}

extern "C" void kernel_launch(void* const* d_in, const int* in_sizes, int n_in,
                              void* d_out, int out_size, void* d_ws, size_t ws_size,
                              hipStream_t stream) {
  (void)in_sizes; (void)n_in; (void)out_size; (void)ws_size;
  const float* query = (const float*)d_in[0];
  const float* key   = (const float*)d_in[1];
  const float* value = (const float*)d_in[2];
  const int*   mask  = (const int*)d_in[3];
  const float* W1    = (const float*)d_in[4];
  const float* b1    = (const float*)d_in[5];
  const float* W2    = (const float*)d_in[6];
  const float* b2    = (const float*)d_in[7];
  const float* W3    = (const float*)d_in[8];
  const float* b3    = (const float*)d_in[9];

  float* out  = (float*)d_out;                 // (B,LQ,D)   = 262144 floats
  float* attn = out + B_ * LQ_ * D_;           // (B,LQ,LK)  = 524288 floats

  float*  qp  = (float*)d_ws;                  // (B*LQ, H1) fp32
  float*  kp  = qp + B_ * LQ_ * H1_;           // (B*LK, H1) fp32
  __bf16* w2t = (__bf16*)(kp + B_ * LK_ * H1_);// (H2, H1) bf16

  prep_kernel<<<384, 256, 0, stream>>>(query, key, W1, b1, W2, qp, kp, w2t);
  dim3 gscore(LK_ / 16, LQ_ / 8, B_);
  score_kernel<<<gscore, 256, 0, stream>>>(qp, kp, w2t, b2, W3, b3, attn);
  softmax_kernel<<<B_ * LQ_, 256, 0, stream>>>(attn, mask);
  out_kernel<<<128, 256, 0, stream>>>(attn, value, out);
}

// Round 3
// 154.757 us; speedup vs baseline: 1.2851x; 1.2851x over previous
//
#include <hip/hip_runtime.h>

#define D_  256
#define H1_ 256
#define H2_ 128
#define B_  2
#define LQ_ 512
#define LK_ 512
#define BK  64

typedef float  f32x4  __attribute__((ext_vector_type(4)));
typedef __bf16 bf16x8 __attribute__((ext_vector_type(8)));
typedef __bf16 bf16x4 __attribute__((ext_vector_type(4)));

// ---- prep: qp = query@W1[:D] + b1 ; kp = key@W1[D:] ; w2t = bf16(W2^T) ----
// 512 threads: h = tid&255 (output col), kh = tid>>8 (k-half). In-block k-split
// halves the serial FMA chain; LDS combine at the end.
__global__ __launch_bounds__(512) void prep_kernel(
    const float* __restrict__ query, const float* __restrict__ key,
    const float* __restrict__ W1, const float* __restrict__ b1,
    const float* __restrict__ W2,
    float* __restrict__ qp, float* __restrict__ kp, __bf16* __restrict__ w2t) {
  const int blk = blockIdx.x;
  const int tid = threadIdx.x;
  if (blk >= 256) {
    // 64 blocks x 512 threads = 32768 = H2*H1 elements of W2^T (bf16)
    const int id = (blk - 256) * 512 + tid;
    const int n = id >> 8;    // H2 index
    const int k = id & 255;   // H1 index
    w2t[n * H1_ + k] = (__bf16)W2[k * H2_ + n];
    return;
  }
  __shared__ float in_lds[8][D_];
  __shared__ float part[8][H1_];
  const int row0 = blk * 8;              // rows 0..1023 -> qp, 1024.. -> kp
  const int sel  = row0 >> 10;
  const float* __restrict__ src = sel ? key : query;
  const int base = (row0 & 1023) * D_;
  for (int i = tid; i < 8 * D_; i += 512)
    in_lds[i >> 8][i & 255] = src[base + i];
  __syncthreads();
  const int h  = tid & 255;
  const int kh = tid >> 8;
  float acc[8] = {0.f, 0.f, 0.f, 0.f, 0.f, 0.f, 0.f, 0.f};
  const float* __restrict__ w = W1 + sel * D_ * H1_ + kh * 128 * H1_ + h;
#pragma unroll 4
  for (int dd = 0; dd < 128; ++dd) {
    const float wv = w[dd * H1_];
    const int d = kh * 128 + dd;
#pragma unroll
    for (int r = 0; r < 8; ++r) acc[r] += in_lds[r][d] * wv;
  }
  if (kh == 1) {
#pragma unroll
    for (int r = 0; r < 8; ++r) part[r][h] = acc[r];
  }
  __syncthreads();
  if (kh == 0) {
    const float bias = sel ? 0.0f : b1[h];
    float* __restrict__ dst = sel ? kp : qp;
#pragma unroll
    for (int r = 0; r < 8; ++r)
      dst[base + r * H1_ + h] = acc[r] + part[r][h] + bias;
  }
}

// ---- main fused kernel: scores[b, q0+qi, k0+ki] for 8 q x 16 k per block ----
// (unchanged — verified correct + timing-stable in R1)
__global__ __launch_bounds__(256, 2) void score_kernel(
    const float* __restrict__ qp, const float* __restrict__ kp,
    const __bf16* __restrict__ w2t,
    const float* __restrict__ b2, const float* __restrict__ W3,
    const float* __restrict__ b3, float* __restrict__ scores) {
  __shared__ __bf16 A_lds[128][BK + 8];
  __shared__ __bf16 B_lds[128][BK + 8];
  __shared__ float  spart[2][128];

  const int b  = blockIdx.z;
  const int q0 = blockIdx.y * 8;
  const int k0 = blockIdx.x * 16;
  const int tid  = threadIdx.x;
  const int wave = tid >> 6;
  const int lane = tid & 63;
  const int quad = lane >> 4;
  const int l16  = lane & 15;
  const int wm   = wave >> 1;
  const int wn   = wave & 1;

  const float* __restrict__ qpb = qp + (b * LQ_ + q0) * H1_;
  const float* __restrict__ kpb = kp + (b * LK_ + k0) * H1_;

  f32x4 acc[4][4];
#pragma unroll
  for (int mt = 0; mt < 4; ++mt)
#pragma unroll
    for (int nt = 0; nt < 4; ++nt)
      acc[mt][nt] = (f32x4){0.f, 0.f, 0.f, 0.f};

  for (int kc = 0; kc < H1_ / BK; ++kc) {
#pragma unroll
    for (int i = 0; i < 8; ++i) {
      const int r  = i * 16 + (tid >> 4);
      const int kg = tid & 15;
      const int qi = r >> 4, ki = r & 15;
      const int kcol = kc * BK + kg * 4;
      const float4 qv = *(const float4*)(qpb + qi * H1_ + kcol);
      const float4 kv = *(const float4*)(kpb + ki * H1_ + kcol);
      bf16x4 a;
      a[0] = (__bf16)fmaxf(qv.x + kv.x, 0.f);
      a[1] = (__bf16)fmaxf(qv.y + kv.y, 0.f);
      a[2] = (__bf16)fmaxf(qv.z + kv.z, 0.f);
      a[3] = (__bf16)fmaxf(qv.w + kv.w, 0.f);
      *(bf16x4*)(&A_lds[r][kg * 4]) = a;
    }
#pragma unroll
    for (int i = 0; i < 4; ++i) {
      const int u = i * 256 + tid;
      const int n = u >> 3, seg = u & 7;
      *(uint4*)(&B_lds[n][seg * 8]) =
          *(const uint4*)(w2t + n * H1_ + kc * BK + seg * 8);
    }
    __syncthreads();
#pragma unroll
    for (int ks = 0; ks < BK / 32; ++ks) {
      bf16x8 af[4], bfr[4];
#pragma unroll
      for (int mt = 0; mt < 4; ++mt)
        af[mt] = *(const bf16x8*)(&A_lds[wm * 64 + mt * 16 + l16][ks * 32 + quad * 8]);
#pragma unroll
      for (int nt = 0; nt < 4; ++nt)
        bfr[nt] = *(const bf16x8*)(&B_lds[wn * 64 + nt * 16 + l16][ks * 32 + quad * 8]);
#pragma unroll
      for (int mt = 0; mt < 4; ++mt)
#pragma unroll
        for (int nt = 0; nt < 4; ++nt)
          acc[mt][nt] = __builtin_amdgcn_mfma_f32_16x16x32_bf16(
              af[mt], bfr[nt], acc[mt][nt], 0, 0, 0);
    }
    __syncthreads();
  }

  float part[4][4];
#pragma unroll
  for (int mt = 0; mt < 4; ++mt)
#pragma unroll
    for (int rg = 0; rg < 4; ++rg) part[mt][rg] = 0.f;
#pragma unroll
  for (int nt = 0; nt < 4; ++nt) {
    const int col = wn * 64 + nt * 16 + l16;
    const float b2v = b2[col];
    const float w3v = W3[col];
#pragma unroll
    for (int mt = 0; mt < 4; ++mt)
#pragma unroll
      for (int rg = 0; rg < 4; ++rg) {
        float h2 = acc[mt][nt][rg] + b2v;
        h2 = fmaxf(h2, 0.f);
        part[mt][rg] += h2 * w3v;
      }
  }
#pragma unroll
  for (int off = 1; off < 16; off <<= 1)
#pragma unroll
    for (int mt = 0; mt < 4; ++mt)
#pragma unroll
      for (int rg = 0; rg < 4; ++rg)
        part[mt][rg] += __shfl_xor(part[mt][rg], off, 64);
  if (l16 == 0) {
#pragma unroll
    for (int mt = 0; mt < 4; ++mt)
#pragma unroll
      for (int rg = 0; rg < 4; ++rg) {
        const int rl = wm * 64 + mt * 16 + quad * 4 + rg;
        spart[wn][rl] = part[mt][rg];
      }
  }
  __syncthreads();
  if (tid < 128) {
    const float s = spart[0][tid] + spart[1][tid] + b3[0];
    const int qi = tid >> 4, ki = tid & 15;
    scores[(b * LQ_ + q0 + qi) * LK_ + k0 + ki] = s;
  }
}

// ---- softmax over k per (b,q) row, with mask; in-place on the attn region ----
__global__ void softmax_kernel(float* __restrict__ attn,
                               const int* __restrict__ mask) {
  const int row = blockIdx.x;
  const int tid = threadIdx.x;
  __shared__ float redm[4];
  __shared__ float reds[4];
  float* __restrict__ arow = attn + row * LK_;
  const int* __restrict__ mrow = mask + row * LK_;
  float s0 = arow[tid], s1 = arow[tid + 256];
  if (mrow[tid] == 0)       s0 = -1e9f;
  if (mrow[tid + 256] == 0) s1 = -1e9f;
  float m = fmaxf(s0, s1);
#pragma unroll
  for (int off = 32; off; off >>= 1) m = fmaxf(m, __shfl_xor(m, off, 64));
  if ((tid & 63) == 0) redm[tid >> 6] = m;
  __syncthreads();
  m = fmaxf(fmaxf(redm[0], redm[1]), fmaxf(redm[2], redm[3]));
  const float e0 = __expf(s0 - m), e1 = __expf(s1 - m);
  float sum = e0 + e1;
#pragma unroll
  for (int off = 32; off; off >>= 1) sum += __shfl_xor(sum, off, 64);
  if ((tid & 63) == 0) reds[tid >> 6] = sum;
  __syncthreads();
  sum = reds[0] + reds[1] + reds[2] + reds[3];
  const float inv = 1.f / sum;
  arow[tid]       = e0 * inv;
  arow[tid + 256] = e1 * inv;
}

// ---- out = attn @ value, one kernel, in-block k-split-4 (no global partials)
// grid (2 d-halves, 64 q-groups, B) = 256 blocks x 512 threads.
// thread: d = (tid&127)+ds*128, kh = tid>>7 in [0,4); 8 q-rows, 128-deep k-loop.
__global__ __launch_bounds__(512) void out_kernel2(
    const float* __restrict__ attn, const float* __restrict__ value,
    float* __restrict__ out) {
  const int ds = blockIdx.x, qg = blockIdx.y, b = blockIdx.z;
  const int tid = threadIdx.x;
  __shared__ float a_lds[8][LK_];       // 16 KB
  __shared__ float p_lds[3][8][128];    // 12 KB
  const float* __restrict__ abase = attn + (b * LQ_ + qg * 8) * LK_;
  for (int i = tid; i < 8 * LK_; i += 512)
    a_lds[i >> 9][i & 511] = abase[i];
  __syncthreads();
  const int dl = tid & 127;
  const int d  = dl + ds * 128;
  const int kh = tid >> 7;              // 0..3
  float acc[8] = {0.f, 0.f, 0.f, 0.f, 0.f, 0.f, 0.f, 0.f};
  const float* __restrict__ vb = value + (b * LK_ + kh * 128) * D_ + d;
#pragma unroll 4
  for (int k = 0; k < 128; ++k) {
    const float v = vb[k * D_];
    const float* __restrict__ ar = &a_lds[0][kh * 128 + k];
#pragma unroll
    for (int q = 0; q < 8; ++q) acc[q] += ar[q * LK_] * v;
  }
  if (kh > 0) {
#pragma unroll
    for (int q = 0; q < 8; ++q) p_lds[kh - 1][q][dl] = acc[q];
  }
  __syncthreads();
  if (kh == 0) {
    float* __restrict__ ob = out + (b * LQ_ + qg * 8) * D_ + d;
#pragma unroll
    for (int q = 0; q < 8; ++q)
      ob[q * D_] = acc[q] + p_lds[0][q][dl] + p_lds[1][q][dl] + p_lds[2][q][dl];
  }
}

extern "C" void kernel_launch(void* const* d_in, const int* in_sizes, int n_in,
                              void* d_out, int out_size, void* d_ws, size_t ws_size,
                              hipStream_t stream) {
  (void)in_sizes; (void)n_in; (void)out_size; (void)ws_size;
  const float* query = (const float*)d_in[0];
  const float* key   = (const float*)d_in[1];
  const float* value = (const float*)d_in[2];
  const int*   mask  = (const int*)d_in[3];
  const float* W1    = (const float*)d_in[4];
  const float* b1    = (const float*)d_in[5];
  const float* W2    = (const float*)d_in[6];
  const float* b2    = (const float*)d_in[7];
  const float* W3    = (const float*)d_in[8];
  const float* b3    = (const float*)d_in[9];

  float* out  = (float*)d_out;                 // (B,LQ,D)   = 262144 floats
  float* attn = out + B_ * LQ_ * D_;           // (B,LQ,LK)  = 524288 floats

  // ws layout identical to the R1-passing config: qp, kp, w2t. Nothing else
  // touches ws (the R2 global-partials aliasing is gone).
  float*  qp  = (float*)d_ws;                  // (B*LQ, H1) fp32
  float*  kp  = qp + B_ * LQ_ * H1_;           // (B*LK, H1) fp32
  __bf16* w2t = (__bf16*)(kp + B_ * LK_ * H1_);// (H2, H1) bf16

  prep_kernel<<<320, 512, 0, stream>>>(query, key, W1, b1, W2, qp, kp, w2t);
  dim3 gscore(LK_ / 16, LQ_ / 8, B_);
  score_kernel<<<gscore, 256, 0, stream>>>(qp, kp, w2t, b2, W3, b3, attn);
  softmax_kernel<<<B_ * LQ_, 256, 0, stream>>>(attn, mask);
  out_kernel2<<<dim3(2, 64, B_), 512, 0, stream>>>(attn, value, out);
}